// Round 1
// baseline (1348.529 us; speedup 1.0000x reference)
//
#include <hip/hip_runtime.h>
#include <hip/hip_bf16.h>
#include <stdint.h>

#define N_OBS 65536
#define N_DIM 256
#define N_FUN 16
#define N_APP 8
#define MT 64
#define PERM_STRIDE (N_OBS + N_FUN * MT)   // 66560
#define MAX_TILES (PERM_STRIDE / MT)       // 1040

typedef __attribute__((ext_vector_type(8))) short v8s;
typedef __attribute__((ext_vector_type(4))) float v4f;

__device__ __forceinline__ unsigned short f2bf(float f) {
  union { float f; uint32_t u; } v;
  v.f = f;
  uint32_t u = v.u;
  return (unsigned short)((u + 0x7FFFu + ((u >> 16) & 1u)) >> 16);
}

// ---- init: perm = -1, counters = 0 ----
__global__ void k_init(int* __restrict__ perm, int* __restrict__ cnt) {
  int tid = blockIdx.x * 256 + threadIdx.x;
  if (tid < N_APP * PERM_STRIDE) {
    perm[tid] = -1;
  } else {
    int r = tid - N_APP * PERM_STRIDE;
    if (r < N_APP * N_FUN) cnt[r] = 0;
  }
}

// ---- W (f,d,e) f32 -> Wt (f,e,d) bf16  (B-operand friendly: contiguous k) ----
__global__ void k_prep_w(const float* __restrict__ W, unsigned short* __restrict__ Wt) {
  int tid = blockIdx.x * 256 + threadIdx.x;   // tid = f*65536 + n*256 + k
  int f = tid >> 16;
  int n = (tid >> 8) & 255;
  int k = tid & 255;
  Wt[tid] = f2bf(W[(f << 16) | (k << 8) | n]);
}

// ---- histogram of function indices per step ----
__global__ void k_hist(const int* __restrict__ fidx, int* __restrict__ cnt) {
  __shared__ int h[N_APP * N_FUN];
  int tid = threadIdx.x;
  if (tid < N_APP * N_FUN) h[tid] = 0;
  __syncthreads();
  int o = blockIdx.x * 256 + tid;
  const int4* p = (const int4*)(fidx + o * N_APP);
  int4 a = p[0], b = p[1];
  atomicAdd(&h[0 * N_FUN + a.x], 1);
  atomicAdd(&h[1 * N_FUN + a.y], 1);
  atomicAdd(&h[2 * N_FUN + a.z], 1);
  atomicAdd(&h[3 * N_FUN + a.w], 1);
  atomicAdd(&h[4 * N_FUN + b.x], 1);
  atomicAdd(&h[5 * N_FUN + b.y], 1);
  atomicAdd(&h[6 * N_FUN + b.z], 1);
  atomicAdd(&h[7 * N_FUN + b.w], 1);
  __syncthreads();
  if (tid < N_APP * N_FUN) atomicAdd(&cnt[tid], h[tid]);
}

// ---- exclusive scan with padding to MT; fill tile->f map; init cursors ----
__global__ void k_scan(const int* __restrict__ cnt, int* __restrict__ pb,
                       int* __restrict__ cursor, int* __restrict__ tilef) {
  int t = threadIdx.x;
  if (t >= N_APP) return;
  int base = 0;
  for (int f = 0; f < N_FUN; ++f) {
    pb[t * 17 + f] = base;
    cursor[t * N_FUN + f] = base;
    int c = cnt[t * N_FUN + f];
    int padded = (c + MT - 1) & ~(MT - 1);
    int q0 = base / MT, q1 = (base + padded) / MT;
    for (int q = q0; q < q1; ++q) tilef[t * MAX_TILES + q] = f;
    base += padded;
  }
  pb[t * 17 + 16] = base;
}

// ---- scatter row ids into per-(step,function) groups ----
__global__ void k_scatter(const int* __restrict__ fidx, int* __restrict__ cursor,
                          int* __restrict__ perm) {
  int o = blockIdx.x * 256 + threadIdx.x;
  const int4* p = (const int4*)(fidx + o * N_APP);
  int4 a = p[0], b = p[1];
  int fs[8] = {a.x, a.y, a.z, a.w, b.x, b.y, b.z, b.w};
  #pragma unroll
  for (int t = 0; t < N_APP; ++t) {
    int pos = atomicAdd(&cursor[t * N_FUN + fs[t]], 1);
    perm[t * PERM_STRIDE + pos] = o;
  }
}

// ---- one application step: gather rows, grouped GEMM vs W[f], scatter out ----
template <bool SRC_F32, bool DST_F32>
__global__ __launch_bounds__(256, 2)
void k_step(const void* __restrict__ src_, void* __restrict__ dst_,
            const unsigned short* __restrict__ Wt, const float* __restrict__ bias,
            const int* __restrict__ perm_t, const int* __restrict__ pb_t,
            const int* __restrict__ tilef_t) {
  __shared__ unsigned short As[MT * N_DIM];   // 32 KB, XOR-swizzled
  int tile = blockIdx.x;
  if (tile * MT >= pb_t[16]) return;
  int f = tilef_t[tile];
  int tid = threadIdx.x;
  const int* permBase = perm_t + tile * MT;

  // stage A: 64 rows x 256 bf16 (2048 x 16B chunks), swizzle byte ^= (row&7)<<4
  #pragma unroll
  for (int i = 0; i < 8; ++i) {
    int chunk = tid + i * 256;
    int row = chunk >> 5;
    int c = chunk & 31;
    int grow = permBase[row];
    unsigned short* d =
        (unsigned short*)((char*)As + (row << 9) + ((c << 4) ^ ((row & 7) << 4)));
    v8s val = {0, 0, 0, 0, 0, 0, 0, 0};
    if (grow >= 0) {
      if (SRC_F32) {
        const v4f* s = (const v4f*)((const float*)src_ + ((size_t)grow << 8) + (c << 3));
        v4f v0 = s[0], v1 = s[1];
        val[0] = (short)f2bf(v0[0]);
        val[1] = (short)f2bf(v0[1]);
        val[2] = (short)f2bf(v0[2]);
        val[3] = (short)f2bf(v0[3]);
        val[4] = (short)f2bf(v1[0]);
        val[5] = (short)f2bf(v1[1]);
        val[6] = (short)f2bf(v1[2]);
        val[7] = (short)f2bf(v1[3]);
      } else {
        val = *(const v8s*)((const unsigned short*)src_ + ((size_t)grow << 8) + (c << 3));
      }
    }
    *(v8s*)d = val;
  }
  __syncthreads();

  int lane = tid & 63;
  int wave = tid >> 6;     // 4 waves, wave w owns n in [w*64, w*64+64)
  int l15 = lane & 15;
  int lq = lane >> 4;

  v4f acc[4][4] = {};
  const unsigned short* Wf = Wt + (size_t)f * N_DIM * N_DIM;

  #pragma unroll
  for (int kk = 0; kk < 8; ++kk) {
    v8s a[4];
    #pragma unroll
    for (int mt = 0; mt < 4; ++mt) {
      int row = mt * 16 + l15;
      int byte = (row << 9) + ((((kk << 2) + lq) << 4) ^ ((row & 7) << 4));
      a[mt] = *(const v8s*)((const char*)As + byte);
    }
    #pragma unroll
    for (int nt = 0; nt < 4; ++nt) {
      int n = wave * 64 + nt * 16 + l15;
      v8s bfr = *(const v8s*)(Wf + n * N_DIM + (kk << 5) + (lq << 3));
      #pragma unroll
      for (int mt = 0; mt < 4; ++mt)
        acc[mt][nt] = __builtin_amdgcn_mfma_f32_16x16x32_bf16(a[mt], bfr, acc[mt][nt], 0, 0, 0);
    }
  }

  int grows[4][4];
  #pragma unroll
  for (int mt = 0; mt < 4; ++mt)
    #pragma unroll
    for (int r = 0; r < 4; ++r)
      grows[mt][r] = permBase[mt * 16 + lq * 4 + r];

  const float* bf_ = bias + f * N_DIM;
  #pragma unroll
  for (int nt = 0; nt < 4; ++nt) {
    int n = wave * 64 + nt * 16 + l15;
    float bv = bf_[n];
    #pragma unroll
    for (int mt = 0; mt < 4; ++mt) {
      #pragma unroll
      for (int r = 0; r < 4; ++r) {
        int grow = grows[mt][r];
        if (grow >= 0) {
          float v = acc[mt][nt][r] + bv;
          if (DST_F32)
            ((float*)dst_)[((size_t)grow << 8) + n] = v;
          else
            ((unsigned short*)dst_)[((size_t)grow << 8) + n] = f2bf(v);
        }
      }
    }
  }
}

extern "C" void kernel_launch(void* const* d_in, const int* in_sizes, int n_in,
                              void* d_out, int out_size, void* d_ws, size_t ws_size,
                              hipStream_t stream) {
  const float* x = (const float*)d_in[0];
  const int* fidx = (const int*)d_in[1];
  const float* W = (const float*)d_in[2];
  const float* bias = (const float*)d_in[3];

  char* ws = (char*)d_ws;
  unsigned short* carryA = (unsigned short*)ws;                       // 32 MB
  unsigned short* Wt = (unsigned short*)(ws + (size_t)33554432);      // 2 MB
  int* perm   = (int*)(ws + 35651584);                                // 8*66560*4
  int* cnt    = (int*)(ws + 37781504);                                // 512 B
  int* cursor = (int*)(ws + 37782016);                                // 512 B
  int* pb     = (int*)(ws + 37782528);                                // 8*17*4
  int* tilef  = (int*)(ws + 37783072);                                // 8*1040*4
  unsigned short* carryB = (unsigned short*)d_out;  // bf16 scratch in d_out (t<7)

  k_init<<<(N_APP * PERM_STRIDE + N_APP * N_FUN + 255) / 256, 256, 0, stream>>>(perm, cnt);
  k_prep_w<<<(N_FUN * N_DIM * N_DIM) / 256, 256, 0, stream>>>(W, Wt);
  k_hist<<<N_OBS / 256, 256, 0, stream>>>(fidx, cnt);
  k_scan<<<1, 64, 0, stream>>>(cnt, pb, cursor, tilef);
  k_scatter<<<N_OBS / 256, 256, 0, stream>>>(fidx, cursor, perm);

  // t=0: x(f32) -> carryA ; t odd: A->B ; t even: B->A ; t=7: A -> d_out(f32)
  k_step<true, false><<<MAX_TILES, 256, 0, stream>>>(x, carryA, Wt, bias, perm, pb, tilef);
  for (int t = 1; t < 7; ++t) {
    const unsigned short* s = (t & 1) ? carryA : carryB;
    unsigned short* d = (t & 1) ? carryB : carryA;
    k_step<false, false><<<MAX_TILES, 256, 0, stream>>>(
        s, d, Wt, bias, perm + t * PERM_STRIDE, pb + t * 17, tilef + t * MAX_TILES);
  }
  k_step<false, true><<<MAX_TILES, 256, 0, stream>>>(
      carryA, d_out, Wt, bias, perm + 7 * PERM_STRIDE, pb + 7 * 17, tilef + 7 * MAX_TILES);
}

// Round 2
// 443.298 us; speedup vs baseline: 3.0420x; 3.0420x over previous
//
#include <hip/hip_runtime.h>
#include <hip/hip_bf16.h>
#include <stdint.h>

#define N_OBS 65536
#define N_DIM 256
#define N_FUN 16
#define N_APP 8
#define MT 64
#define PERM_STRIDE (N_OBS + N_FUN * MT)   // 66560
#define MAX_TILES (PERM_STRIDE / MT)       // 1040
#define N_BLK 256                          // scatter blocks (65536/256)

typedef __attribute__((ext_vector_type(8))) short v8s;
typedef __attribute__((ext_vector_type(4))) float v4f;

__device__ __forceinline__ unsigned short f2bf(float f) {
  union { float f; uint32_t u; } v;
  v.f = f;
  uint32_t u = v.u;
  return (unsigned short)((u + 0x7FFFu + ((u >> 16) & 1u)) >> 16);
}

// ---- init: perm = -1 ----
__global__ void k_init(int* __restrict__ perm) {
  int tid = blockIdx.x * 256 + threadIdx.x;
  if (tid < N_APP * PERM_STRIDE) perm[tid] = -1;
}

// ---- W (f,d,e) f32 -> Wt (f,e,d) bf16  (B-operand friendly: contiguous k) ----
__global__ void k_prep_w(const float* __restrict__ W, unsigned short* __restrict__ Wt) {
  int tid = blockIdx.x * 256 + threadIdx.x;   // tid = f*65536 + n*256 + k
  int f = tid >> 16;
  int n = (tid >> 8) & 255;
  int k = tid & 255;
  Wt[tid] = f2bf(W[(f << 16) | (k << 8) | n]);
}

// ---- per-block histogram: blockCnt[(t*16+f)*N_BLK + b] ----
__global__ void k_hist2(const int* __restrict__ fidx, int* __restrict__ blockCnt) {
  __shared__ int h[N_APP * N_FUN];
  int tid = threadIdx.x;
  if (tid < N_APP * N_FUN) h[tid] = 0;
  __syncthreads();
  int o = blockIdx.x * 256 + tid;
  const int4* p = (const int4*)(fidx + o * N_APP);
  int4 a = p[0], b = p[1];
  atomicAdd(&h[0 * N_FUN + a.x], 1);
  atomicAdd(&h[1 * N_FUN + a.y], 1);
  atomicAdd(&h[2 * N_FUN + a.z], 1);
  atomicAdd(&h[3 * N_FUN + a.w], 1);
  atomicAdd(&h[4 * N_FUN + b.x], 1);
  atomicAdd(&h[5 * N_FUN + b.y], 1);
  atomicAdd(&h[6 * N_FUN + b.z], 1);
  atomicAdd(&h[7 * N_FUN + b.w], 1);
  __syncthreads();
  if (tid < N_APP * N_FUN) blockCnt[tid * N_BLK + blockIdx.x] = h[tid];
}

// ---- totals -> padded bases -> per-block offsets; fill tile->f map ----
__global__ void k_scan2(const int* __restrict__ blockCnt, int* __restrict__ pb,
                        int* __restrict__ tilef, int* __restrict__ blockOff) {
  __shared__ int tot[N_APP * N_FUN];
  int i = threadIdx.x;   // 128 threads: i = t*16+f
  if (i < N_APP * N_FUN) {
    int s = 0;
    for (int b = 0; b < N_BLK; ++b) s += blockCnt[i * N_BLK + b];
    tot[i] = s;
  }
  __syncthreads();
  if (i < N_APP) {
    int base = 0;
    for (int f = 0; f < N_FUN; ++f) {
      pb[i * 17 + f] = base;
      int c = tot[i * N_FUN + f];
      int padded = (c + MT - 1) & ~(MT - 1);
      int q0 = base / MT, q1 = (base + padded) / MT;
      for (int q = q0; q < q1; ++q) tilef[i * MAX_TILES + q] = f;
      base += padded;
    }
    pb[i * 17 + 16] = base;
  }
  __syncthreads();
  if (i < N_APP * N_FUN) {
    int t = i >> 4, f = i & 15;
    int off = pb[t * 17 + f];
    for (int b = 0; b < N_BLK; ++b) {
      blockOff[i * N_BLK + b] = off;
      off += blockCnt[i * N_BLK + b];
    }
  }
}

// ---- scatter via per-block LDS cursors (no global atomics) ----
__global__ void k_scatter2(const int* __restrict__ fidx, const int* __restrict__ blockOff,
                           int* __restrict__ perm) {
  __shared__ int cur[N_APP * N_FUN];
  int tid = threadIdx.x;
  if (tid < N_APP * N_FUN) cur[tid] = blockOff[tid * N_BLK + blockIdx.x];
  __syncthreads();
  int o = blockIdx.x * 256 + tid;
  const int4* p = (const int4*)(fidx + o * N_APP);
  int4 a = p[0], b = p[1];
  int fs[8] = {a.x, a.y, a.z, a.w, b.x, b.y, b.z, b.w};
  #pragma unroll
  for (int t = 0; t < N_APP; ++t) {
    int pos = atomicAdd(&cur[t * N_FUN + fs[t]], 1);
    perm[t * PERM_STRIDE + pos] = o;
  }
}

// ---- one application step: gather rows, grouped GEMM vs W[f], scatter out ----
template <bool SRC_F32, bool DST_F32>
__global__ __launch_bounds__(256, 2)
void k_step(const void* __restrict__ src_, void* __restrict__ dst_,
            const unsigned short* __restrict__ Wt, const float* __restrict__ bias,
            const int* __restrict__ perm_t, const int* __restrict__ pb_t,
            const int* __restrict__ tilef_t) {
  __shared__ unsigned short As[MT * N_DIM];   // 32 KB, XOR-swizzled
  int tile = blockIdx.x;
  if (tile * MT >= pb_t[16]) return;
  int f = tilef_t[tile];
  int tid = threadIdx.x;
  const int* permBase = perm_t + tile * MT;

  // stage A: 64 rows x 256 bf16 (2048 x 16B chunks), swizzle byte ^= (row&7)<<4
  #pragma unroll
  for (int i = 0; i < 8; ++i) {
    int chunk = tid + i * 256;
    int row = chunk >> 5;
    int c = chunk & 31;
    int grow = permBase[row];
    unsigned short* d =
        (unsigned short*)((char*)As + (row << 9) + ((c << 4) ^ ((row & 7) << 4)));
    v8s val = {0, 0, 0, 0, 0, 0, 0, 0};
    if (grow >= 0) {
      if (SRC_F32) {
        const v4f* s = (const v4f*)((const float*)src_ + ((size_t)grow << 8) + (c << 3));
        v4f v0 = s[0], v1 = s[1];
        val[0] = (short)f2bf(v0[0]);
        val[1] = (short)f2bf(v0[1]);
        val[2] = (short)f2bf(v0[2]);
        val[3] = (short)f2bf(v0[3]);
        val[4] = (short)f2bf(v1[0]);
        val[5] = (short)f2bf(v1[1]);
        val[6] = (short)f2bf(v1[2]);
        val[7] = (short)f2bf(v1[3]);
      } else {
        val = *(const v8s*)((const unsigned short*)src_ + ((size_t)grow << 8) + (c << 3));
      }
    }
    *(v8s*)d = val;
  }
  __syncthreads();

  int lane = tid & 63;
  int wave = tid >> 6;     // 4 waves, wave w owns n in [w*64, w*64+64)
  int l15 = lane & 15;
  int lq = lane >> 4;

  v4f acc[4][4] = {};
  const unsigned short* Wf = Wt + (size_t)f * N_DIM * N_DIM;

  #pragma unroll
  for (int kk = 0; kk < 8; ++kk) {
    v8s a[4];
    #pragma unroll
    for (int mt = 0; mt < 4; ++mt) {
      int row = mt * 16 + l15;
      int byte = (row << 9) + ((((kk << 2) + lq) << 4) ^ ((row & 7) << 4));
      a[mt] = *(const v8s*)((const char*)As + byte);
    }
    #pragma unroll
    for (int nt = 0; nt < 4; ++nt) {
      int n = wave * 64 + nt * 16 + l15;
      v8s bfr = *(const v8s*)(Wf + n * N_DIM + (kk << 5) + (lq << 3));
      #pragma unroll
      for (int mt = 0; mt < 4; ++mt)
        acc[mt][nt] = __builtin_amdgcn_mfma_f32_16x16x32_bf16(a[mt], bfr, acc[mt][nt], 0, 0, 0);
    }
  }

  int grows[4][4];
  #pragma unroll
  for (int mt = 0; mt < 4; ++mt)
    #pragma unroll
    for (int r = 0; r < 4; ++r)
      grows[mt][r] = permBase[mt * 16 + lq * 4 + r];

  const float* bf_ = bias + f * N_DIM;
  #pragma unroll
  for (int nt = 0; nt < 4; ++nt) {
    int n = wave * 64 + nt * 16 + l15;
    float bv = bf_[n];
    #pragma unroll
    for (int mt = 0; mt < 4; ++mt) {
      #pragma unroll
      for (int r = 0; r < 4; ++r) {
        int grow = grows[mt][r];
        if (grow >= 0) {
          float v = acc[mt][nt][r] + bv;
          if (DST_F32)
            ((float*)dst_)[((size_t)grow << 8) + n] = v;
          else
            ((unsigned short*)dst_)[((size_t)grow << 8) + n] = f2bf(v);
        }
      }
    }
  }
}

extern "C" void kernel_launch(void* const* d_in, const int* in_sizes, int n_in,
                              void* d_out, int out_size, void* d_ws, size_t ws_size,
                              hipStream_t stream) {
  const float* x = (const float*)d_in[0];
  const int* fidx = (const int*)d_in[1];
  const float* W = (const float*)d_in[2];
  const float* bias = (const float*)d_in[3];

  char* ws = (char*)d_ws;
  unsigned short* carryA = (unsigned short*)ws;                       // 32 MB
  // blockCnt/blockOff overlap carryA: they are dead before step 0 writes it.
  int* blockCnt = (int*)ws;                                           // 128 KB
  int* blockOff = (int*)(ws + 131072);                                // 128 KB
  unsigned short* Wt = (unsigned short*)(ws + (size_t)33554432);      // 2 MB
  int* perm   = (int*)(ws + 35651584);                                // 8*66560*4
  int* pb     = (int*)(ws + 37781504);                                // 8*17*4
  int* tilef  = (int*)(ws + 37782048);                                // 8*1040*4
  unsigned short* carryB = (unsigned short*)d_out;  // bf16 scratch in d_out (t<7)

  k_init<<<(N_APP * PERM_STRIDE + 255) / 256, 256, 0, stream>>>(perm);
  k_prep_w<<<(N_FUN * N_DIM * N_DIM) / 256, 256, 0, stream>>>(W, Wt);
  k_hist2<<<N_BLK, 256, 0, stream>>>(fidx, blockCnt);
  k_scan2<<<1, 128, 0, stream>>>(blockCnt, pb, tilef, blockOff);
  k_scatter2<<<N_BLK, 256, 0, stream>>>(fidx, blockOff, perm);

  // t=0: x(f32) -> carryA ; t odd: A->B ; t even: B->A ; t=7: A -> d_out(f32)
  k_step<true, false><<<MAX_TILES, 256, 0, stream>>>(x, carryA, Wt, bias, perm, pb, tilef);
  for (int t = 1; t < 7; ++t) {
    const unsigned short* s = (t & 1) ? carryA : carryB;
    unsigned short* d = (t & 1) ? carryB : carryA;
    k_step<false, false><<<MAX_TILES, 256, 0, stream>>>(
        s, d, Wt, bias, perm + t * PERM_STRIDE, pb + t * 17, tilef + t * MAX_TILES);
  }
  k_step<false, true><<<MAX_TILES, 256, 0, stream>>>(
      carryA, d_out, Wt, bias, perm + 7 * PERM_STRIDE, pb + 7 * 17, tilef + 7 * MAX_TILES);
}

// Round 3
// 388.087 us; speedup vs baseline: 3.4748x; 1.1423x over previous
//
#include <hip/hip_runtime.h>
#include <hip/hip_bf16.h>
#include <stdint.h>

#define N_OBS 65536
#define N_DIM 256
#define N_FUN 16
#define N_APP 8
#define MT 64
#define PERM_STRIDE (N_OBS + N_FUN * MT)   // 66560
#define MAX_TILES (PERM_STRIDE / MT)       // 1040
#define N_BLK 256                          // hist/scatter blocks

typedef __attribute__((ext_vector_type(8))) short v8s;
typedef __attribute__((ext_vector_type(4))) short v4s;
typedef __attribute__((ext_vector_type(4))) float v4f;

__device__ __forceinline__ unsigned short f2bf(float f) {
  union { float f; uint32_t u; } v;
  v.f = f;
  uint32_t u = v.u;
  return (unsigned short)((u + 0x7FFFu + ((u >> 16) & 1u)) >> 16);
}

// ---- init: perm = -1 ----
__global__ void k_init(int* __restrict__ perm) {
  int tid = blockIdx.x * 256 + threadIdx.x;
  if (tid < N_APP * PERM_STRIDE) perm[tid] = -1;
}

// ---- W (f,d,e) f32 -> Wt (f,e,d) bf16 ----
__global__ void k_prep_w(const float* __restrict__ W, unsigned short* __restrict__ Wt) {
  int tid = blockIdx.x * 256 + threadIdx.x;   // tid = f*65536 + n*256 + k
  int f = tid >> 16;
  int n = (tid >> 8) & 255;
  int k = tid & 255;
  Wt[tid] = f2bf(W[(f << 16) | (k << 8) | n]);
}

// ---- per-block histogram ----
__global__ void k_hist2(const int* __restrict__ fidx, int* __restrict__ blockCnt) {
  __shared__ int h[N_APP * N_FUN];
  int tid = threadIdx.x;
  if (tid < N_APP * N_FUN) h[tid] = 0;
  __syncthreads();
  int o = blockIdx.x * 256 + tid;
  const int4* p = (const int4*)(fidx + o * N_APP);
  int4 a = p[0], b = p[1];
  atomicAdd(&h[0 * N_FUN + a.x], 1);
  atomicAdd(&h[1 * N_FUN + a.y], 1);
  atomicAdd(&h[2 * N_FUN + a.z], 1);
  atomicAdd(&h[3 * N_FUN + a.w], 1);
  atomicAdd(&h[4 * N_FUN + b.x], 1);
  atomicAdd(&h[5 * N_FUN + b.y], 1);
  atomicAdd(&h[6 * N_FUN + b.z], 1);
  atomicAdd(&h[7 * N_FUN + b.w], 1);
  __syncthreads();
  if (tid < N_APP * N_FUN) blockCnt[tid * N_BLK + blockIdx.x] = h[tid];
}

// ---- totals -> padded bases -> per-block offsets; tile->f map ----
__global__ void k_scan2(const int* __restrict__ blockCnt, int* __restrict__ pb,
                        int* __restrict__ tilef, int* __restrict__ blockOff) {
  __shared__ int tot[N_APP * N_FUN];
  int i = threadIdx.x;   // 128 threads: i = t*16+f
  if (i < N_APP * N_FUN) {
    int s = 0;
    for (int b = 0; b < N_BLK; ++b) s += blockCnt[i * N_BLK + b];
    tot[i] = s;
  }
  __syncthreads();
  if (i < N_APP) {
    int base = 0;
    for (int f = 0; f < N_FUN; ++f) {
      pb[i * 17 + f] = base;
      int c = tot[i * N_FUN + f];
      int padded = (c + MT - 1) & ~(MT - 1);
      int q0 = base / MT, q1 = (base + padded) / MT;
      for (int q = q0; q < q1; ++q) tilef[i * MAX_TILES + q] = f;
      base += padded;
    }
    pb[i * 17 + 16] = base;
  }
  __syncthreads();
  if (i < N_APP * N_FUN) {
    int t = i >> 4, f = i & 15;
    int off = pb[t * 17 + f];
    for (int b = 0; b < N_BLK; ++b) {
      blockOff[i * N_BLK + b] = off;
      off += blockCnt[i * N_BLK + b];
    }
  }
}

// ---- scatter row ids via per-block LDS cursors ----
__global__ void k_scatter2(const int* __restrict__ fidx, const int* __restrict__ blockOff,
                           int* __restrict__ perm) {
  __shared__ int cur[N_APP * N_FUN];
  int tid = threadIdx.x;
  if (tid < N_APP * N_FUN) cur[tid] = blockOff[tid * N_BLK + blockIdx.x];
  __syncthreads();
  int o = blockIdx.x * 256 + tid;
  const int4* p = (const int4*)(fidx + o * N_APP);
  int4 a = p[0], b = p[1];
  int fs[8] = {a.x, a.y, a.z, a.w, b.x, b.y, b.z, b.w};
  #pragma unroll
  for (int t = 0; t < N_APP; ++t) {
    int pos = atomicAdd(&cur[t * N_FUN + fs[t]], 1);
    perm[t * PERM_STRIDE + pos] = o;
  }
}

// ---- pos_t[o] = slot of row o in layout t (t=1..7) ----
__global__ void k_pos(const int* __restrict__ perm, int* __restrict__ pos) {
  int tid = blockIdx.x * 256 + threadIdx.x;
  if (tid >= 7 * PERM_STRIDE) return;
  int t = tid / PERM_STRIDE + 1;   // 1..7
  int s = tid - (t - 1) * PERM_STRIDE;
  int o = perm[t * PERM_STRIDE + s];
  if (o >= 0) pos[(t - 1) * N_OBS + o] = s;
}

// ---- outpos[t][s] = pos_{t+1}[perm[t][s]]  (t=0..6); in-place for t>=1 ----
__global__ void k_outpos(int* __restrict__ perm, const int* __restrict__ pos,
                         int* __restrict__ outpos0) {
  int tid = blockIdx.x * 256 + threadIdx.x;
  if (tid >= 7 * PERM_STRIDE) return;
  int t = tid / PERM_STRIDE;       // 0..6
  int s = tid - t * PERM_STRIDE;
  int o = perm[t * PERM_STRIDE + s];
  int val = (o >= 0) ? pos[t * N_OBS + o] : -1;
  if (t == 0) outpos0[s] = val;
  else perm[t * PERM_STRIDE + s] = val;
}

// ---- one application step ----
// SRC_F32: gather f32 rows from x via perm0. else: contiguous bf16 tile read.
// DST_F32: direct f32 16B/lane stores to outpos rows. else: LDS-staged bf16
//          512B-row writes to outpos slots.
template <int SRC_F32, int DST_F32>
__global__ __launch_bounds__(256, 4)
void k_step(const void* __restrict__ src_, void* __restrict__ dst_,
            const unsigned short* __restrict__ Wt, const float* __restrict__ bias,
            const int* __restrict__ pb_t, const int* __restrict__ tilef_t,
            const int* __restrict__ outpos_t, const int* __restrict__ perm0) {
  __shared__ unsigned short As[MT * N_DIM];   // 32 KB, XOR-swizzled 16B chunks
  __shared__ int ops[MT];
  int tile = blockIdx.x;
  if (tile * MT >= pb_t[16]) return;
  int f = tilef_t[tile];
  int tid = threadIdx.x;

  if (tid < MT) ops[tid] = outpos_t[tile * MT + tid];

  if (SRC_F32) {
    const int* permBase = perm0 + tile * MT;
    #pragma unroll
    for (int i = 0; i < 8; ++i) {
      int g = tid + i * 256;
      int row = g >> 5, c = g & 31;
      int grow = permBase[row];
      if (grow < 0) grow = 0;   // clamp; garbage rows masked at write
      const v4f* s = (const v4f*)((const float*)src_ + ((size_t)grow << 8) + (c << 3));
      v4f v0 = s[0], v1 = s[1];
      v8s val;
      val[0] = (short)f2bf(v0[0]); val[1] = (short)f2bf(v0[1]);
      val[2] = (short)f2bf(v0[2]); val[3] = (short)f2bf(v0[3]);
      val[4] = (short)f2bf(v1[0]); val[5] = (short)f2bf(v1[1]);
      val[6] = (short)f2bf(v1[2]); val[7] = (short)f2bf(v1[3]);
      *(v8s*)((char*)As + (row << 9) + ((c ^ (row & 7)) << 4)) = val;
    }
  } else {
    const unsigned short* srcT = (const unsigned short*)src_ + (size_t)tile * MT * N_DIM;
    #pragma unroll
    for (int i = 0; i < 8; ++i) {
      int g = tid + i * 256;
      int row = g >> 5, c = g & 31;
      v8s val = *(const v8s*)(srcT + (size_t)g * 8);
      *(v8s*)((char*)As + (row << 9) + ((c ^ (row & 7)) << 4)) = val;
    }
  }
  __syncthreads();

  int lane = tid & 63, wave = tid >> 6;
  int l15 = lane & 15, lq = lane >> 4;
  v4f acc[4][4] = {};
  const unsigned short* Wf = Wt + ((size_t)f << 16);

  #pragma unroll
  for (int kk = 0; kk < 8; ++kk) {
    v8s a[4];
    #pragma unroll
    for (int mt = 0; mt < 4; ++mt) {
      int row = mt * 16 + l15;
      int byte = (row << 9) + ((((kk << 2) + lq) ^ (row & 7)) << 4);
      a[mt] = *(const v8s*)((const char*)As + byte);
    }
    #pragma unroll
    for (int nt = 0; nt < 4; ++nt) {
      int n = wave * 64 + nt * 16 + l15;
      v8s bfr = *(const v8s*)(Wf + n * N_DIM + (kk << 5) + (lq << 3));
      #pragma unroll
      for (int mt = 0; mt < 4; ++mt)
        // swapped operands -> C^T layout: lane l15 = row m, lq*4+r = col n
        acc[mt][nt] = __builtin_amdgcn_mfma_f32_16x16x32_bf16(bfr, a[mt], acc[mt][nt], 0, 0, 0);
    }
  }

  const float* bf_ = bias + f * N_DIM;
  if (DST_F32) {
    float* dout = (float*)dst_;
    #pragma unroll
    for (int mt = 0; mt < 4; ++mt) {
      int m = mt * 16 + l15;
      int orow = ops[m];
      if (orow >= 0) {
        #pragma unroll
        for (int nt = 0; nt < 4; ++nt) {
          int n0 = wave * 64 + nt * 16 + lq * 4;
          v4f bv = *(const v4f*)(bf_ + n0);
          v4f o = acc[mt][nt] + bv;
          *(v4f*)(dout + ((size_t)orow << 8) + n0) = o;
        }
      }
    }
  } else {
    __syncthreads();   // all waves done reading As; reuse it to stage C (bf16)
    #pragma unroll
    for (int mt = 0; mt < 4; ++mt) {
      int m = mt * 16 + l15;
      #pragma unroll
      for (int nt = 0; nt < 4; ++nt) {
        int n0 = wave * 64 + nt * 16 + lq * 4;
        v4f bv = *(const v4f*)(bf_ + n0);
        v4s pk;
        pk[0] = (short)f2bf(acc[mt][nt][0] + bv[0]);
        pk[1] = (short)f2bf(acc[mt][nt][1] + bv[1]);
        pk[2] = (short)f2bf(acc[mt][nt][2] + bv[2]);
        pk[3] = (short)f2bf(acc[mt][nt][3] + bv[3]);
        int c = n0 >> 3;                 // 16B chunk within row
        *(v4s*)((char*)As + (m << 9) + ((c ^ (m & 7)) << 4) + ((n0 & 7) << 1)) = pk;
      }
    }
    __syncthreads();
    unsigned short* dst = (unsigned short*)dst_;
    #pragma unroll
    for (int i = 0; i < 8; ++i) {
      int g = tid + i * 256;
      int row = g >> 5, c = g & 31;
      int op = ops[row];
      if (op >= 0) {
        v8s v = *(const v8s*)((char*)As + (row << 9) + ((c ^ (row & 7)) << 4));
        *(v8s*)(dst + (size_t)op * N_DIM + c * 8) = v;
      }
    }
  }
}

extern "C" void kernel_launch(void* const* d_in, const int* in_sizes, int n_in,
                              void* d_out, int out_size, void* d_ws, size_t ws_size,
                              hipStream_t stream) {
  const float* x = (const float*)d_in[0];
  const int* fidx = (const int*)d_in[1];
  const float* W = (const float*)d_in[2];
  const float* bias = (const float*)d_in[3];

  char* ws = (char*)d_ws;
  // carryA: PERM_STRIDE rows x 256 bf16 = 34,078,720 B
  unsigned short* carryA = (unsigned short*)ws;
  // overlap carryA (dead until step 0 writes it):
  int* blockCnt = (int*)ws;                       // 128 KB
  int* blockOff = (int*)(ws + 131072);            // 128 KB
  int* pos      = (int*)(ws + 262144);            // 7*65536*4 = 1.75 MB
  unsigned short* Wt = (unsigned short*)(ws + 34078720);   // 2 MB
  int* perm    = (int*)(ws + 36175872);           // 8*66560*4
  int* pb      = (int*)(ws + 38305792);           // 8*17*4
  int* tilef   = (int*)(ws + 38306336);           // 8*1040*4
  int* outpos0 = (int*)(ws + 38339648);           // 66560*4
  unsigned short* carryB = (unsigned short*)d_out;  // bf16 scratch (34 MB of 64)

  k_init<<<(N_APP * PERM_STRIDE + 255) / 256, 256, 0, stream>>>(perm);
  k_prep_w<<<(N_FUN * N_DIM * N_DIM) / 256, 256, 0, stream>>>(W, Wt);
  k_hist2<<<N_BLK, 256, 0, stream>>>(fidx, blockCnt);
  k_scan2<<<1, 128, 0, stream>>>(blockCnt, pb, tilef, blockOff);
  k_scatter2<<<N_BLK, 256, 0, stream>>>(fidx, blockOff, perm);
  k_pos<<<(7 * PERM_STRIDE + 255) / 256, 256, 0, stream>>>(perm, pos);
  k_outpos<<<(7 * PERM_STRIDE + 255) / 256, 256, 0, stream>>>(perm, pos, outpos0);

  // step 0: gather x(f32) -> carryA (layout-1 slots)
  k_step<1, 0><<<MAX_TILES, 256, 0, stream>>>(x, carryA, Wt, bias, pb, tilef, outpos0, perm);
  // steps 1..6: contiguous bf16 -> next layout slots (outpos in perm[t])
  for (int t = 1; t < 7; ++t) {
    const unsigned short* s = (t & 1) ? carryA : carryB;
    unsigned short* d = (t & 1) ? carryB : carryA;
    k_step<0, 0><<<MAX_TILES, 256, 0, stream>>>(
        s, d, Wt, bias, pb + t * 17, tilef + t * MAX_TILES,
        perm + t * PERM_STRIDE, nullptr);
  }
  // step 7: contiguous bf16 -> d_out f32 at original rows (perm[7])
  k_step<0, 1><<<MAX_TILES, 256, 0, stream>>>(
      carryA, d_out, Wt, bias, pb + 7 * 17, tilef + 7 * MAX_TILES,
      perm + 7 * PERM_STRIDE, nullptr);
}